// Round 6
// baseline (849.172 us; speedup 1.0000x reference)
//
#include <hip/hip_runtime.h>
#include <math.h>

typedef unsigned short ushort_t;
typedef unsigned int uint_t;
typedef __attribute__((ext_vector_type(8))) short bf16x8;
typedef __attribute__((ext_vector_type(4))) float f32x4;

#define NTOK 131072          // B*S
#define TM 16                // tokens per block
// SROW 520: 1040 B row = 65*16 -> b128 16B-aligned; 260 dw == 4 mod 32 -> free
// 2-way bank pattern (SROW=512 would be a 16-way conflict).
#define SROW 520
#define K0P 160              // layer0 Wt row stride AND K extent (132 -> 160)
#define KHS 544              // hidden Wt row STRIDE (1088 B, non-pow2!). K read = 512.
                             // Stride 1024 B (pow2) aliases L2 channels: R4 +244us.
#define EPS 1e-5f

// Hidden-layer k-permutation: the GEMM k-order for hidden layers is arbitrary
// (dot products are permutation-invariant; Wt is transposed in prep anyway).
// Choose k' = 64*w + 4*i + j for output col c = 64*w + 16*j + i (i=c&15 lane,
// j col-tile, w wave). Then each epilogue lane's 4 outputs (j=0..3) are
// CONTIGUOUS in A_s -> one b64 store instead of 12 scatter b16 stores.

__device__ __forceinline__ ushort_t f2bf(float f) {
    uint_t x = __float_as_uint(f);
    x += 0x7FFFu + ((x >> 16) & 1u);   // RNE
    return (ushort_t)(x >> 16);
}
__device__ __forceinline__ float bf2f(ushort_t u) {
    return __uint_as_float(((uint_t)u) << 16);
}

#if defined(__has_builtin)
#  if __has_builtin(__builtin_amdgcn_cvt_pk_bf16_f32)
#    define HAVE_PK_BF16 1
#  endif
#  if __has_builtin(__builtin_amdgcn_rcpf)
#    define HAVE_RCPF 1
#  endif
#endif
__device__ __forceinline__ uint_t pk_bf16(float a, float b) {
#ifdef HAVE_PK_BF16
    auto r = __builtin_amdgcn_cvt_pk_bf16_f32(a, b);
    union { decltype(r) v; uint_t u; } cv; cv.v = r;
    return cv.u;
#else
    return (uint_t)f2bf(a) | ((uint_t)f2bf(b) << 16);
#endif
}
// approx reciprocal: v_rcp_f32 (1 op) vs IEEE div (~9 ops). ~1 ulp; outputs
// are bf16-rounded (tol 1.2e-2) so exactness is not needed.
__device__ __forceinline__ float fastrcp(float x) {
#ifdef HAVE_RCPF
    return __builtin_amdgcn_rcpf(x);
#else
    return 1.0f / x;
#endif
}

// ---- DPP 16-lane rotation-reduction (all-reduce within each 16-lane row) ----
template<int CTRL>
__device__ __forceinline__ float row_ror_add(float v) {
    int r = __builtin_amdgcn_update_dpp(0, __float_as_int(v), CTRL, 0xF, 0xF, true);
    return v + __int_as_float(r);
}
__device__ __forceinline__ float sum16(float v) {
    v = row_ror_add<0x128>(v);   // row_ror:8
    v = row_ror_add<0x124>(v);   // row_ror:4
    v = row_ror_add<0x122>(v);   // row_ror:2
    v = row_ror_add<0x121>(v);   // row_ror:1
    return v;
}

// ---- weight prep (layer 0, unpermuted): W[K][512] -> Wt[n][k] bf16 ----
__global__ __launch_bounds__(256) void prep_w(const float* __restrict__ W,
                                              ushort_t* __restrict__ dst,
                                              int K, int Kpad) {
    int n = blockIdx.x;            // 0..511
    for (int k = threadIdx.x; k < Kpad; k += 256) {
        float v = (k < K) ? W[k * 512 + n] : 0.0f;
        dst[n * Kpad + k] = f2bf(v);
    }
}

// ---- weight prep (hidden layers, k-PERMUTED): Woff = W + 2*512 (te/pos rows
// folded out). dst[n][k'] = Woff[c][n] with c = 64*(k'>>6) + 16*(k'&3) + ((k'>>2)&15).
__global__ __launch_bounds__(256) void prep_w_h(const float* __restrict__ Woff,
                                                ushort_t* __restrict__ dst) {
    int n = blockIdx.x;            // 0..511
    for (int kp = threadIdx.x; kp < KHS; kp += 256) {
        float v = 0.0f;
        if (kp < 512) {
            int wq = kp >> 6, i2 = (kp >> 2) & 15, j2 = kp & 3;
            int c  = 64 * wq + 16 * j2 + i2;
            v = Woff[c * 512 + n];
        }
        dst[n * KHS + kp] = f2bf(v);
    }
}

// ---- cond prep: B*C f32 -> bf16 ONCE (was re-converted per block: ~770
// VALU insts/wave of redundant f2bf — R5 post-mortem) ----
__global__ __launch_bounds__(256) void prep_cond(const float* __restrict__ src,
                                                 ushort_t* __restrict__ dst,
                                                 int n) {
    for (int i = blockIdx.x * 256 + threadIdx.x; i < n; i += gridDim.x * 256)
        dst[i] = f2bf(src[i]);
}

// One fused layer.
//   L0:    tangent GEMMs skipped — tangent pre-acts are W0 rows 2,3 directly.
//   !L0:   GEMM K = 512 (activations only, permuted k-order; Wt matches).
//          te/pos contribution folded into the epilogue bias (f32-exact).
//   LAST:  fuse the final 514->2 linear + divergence into the epilogue
//          (indexed by TRUE col id n — independent of the k-permutation).
template<int KPAD, bool L0, bool LAST>
__device__ __forceinline__ void do_layer(
    const ushort_t* __restrict__ Wt, const float* __restrict__ Wfull, float te,
    const float* __restrict__ bb,
    const float* __restrict__ gg, const float* __restrict__ bev,
    ushort_t* A_s, float* sbuf /*[16][68]*/, float* pwave /*[8][16][8]*/,
    float* dsum /*[16][36]*/, const float* W3s /*[514*2]*/)
{
    const int tid  = threadIdx.x;
    const int w    = tid >> 6;      // wave 0..7
    const int lane = tid & 63;
    const int q    = lane >> 4;     // quad 0..3
    const int c16  = lane & 15;
    const int nb   = w * 64;        // wave's 64-column base

    constexpr int MT  = L0 ? 1 : 3;             // m-tiles in the GEMM
    constexpr int NKS = L0 ? (K0P / 32) : 16;   // K steps actually read

    f32x4 acc[MT][4];
#pragma unroll
    for (int m = 0; m < MT; m++)
#pragma unroll
        for (int j = 0; j < 4; j++) acc[m][j] = (f32x4){0.f, 0.f, 0.f, 0.f};

    const int koff = q * 8;
    const ushort_t* bp = Wt + (nb + c16) * KPAD + koff;
    const ushort_t* ap = A_s + c16 * SROW + koff;

#pragma unroll
    for (int ks = 0; ks < NKS; ks++) {
        bf16x8 af[MT], bf[4];
#pragma unroll
        for (int m = 0; m < MT; m++)
            af[m] = *(const bf16x8*)(ap + m * 16 * SROW + ks * 32);
#pragma unroll
        for (int j = 0; j < 4; j++)
            bf[j] = *(const bf16x8*)(bp + j * 16 * KPAD + ks * 32);
#pragma unroll
        for (int m = 0; m < MT; m++)
#pragma unroll
            for (int j = 0; j < 4; j++)
                acc[m][j] = __builtin_amdgcn_mfma_f32_16x16x32_bf16(af[m], bf[j], acc[m][j], 0, 0, 0);
    }

    // L0: tangent pre-activations direct from W0 rows 2,3 (token-independent).
    // !L0: te/pos fold vectors from W rows 0,1 (f32, L2-resident).
    float tu0[4], tu1[4];
    float w0te[4], w1v[4];
#pragma unroll
    for (int j = 0; j < 4; j++) {
        int n = nb + 16 * j + c16;
        if constexpr (L0) {
            tu0[j] = Wfull[2 * 512 + n];
            tu1[j] = Wfull[3 * 512 + n];
        } else {
            w0te[j] = te * Wfull[n];        // row 0 (te)
            w1v[j]  = Wfull[512 + n];       // row 1 (pos)
        }
    }

    // per-token pos values for this wave's 4 r-slots (token = 4q+r)
    const int si0 = (blockIdx.x * TM) & 63;     // no wrap within a block (16|64)
    float posr[4];
#pragma unroll
    for (int r = 0; r < 4; r++)
        posr[r] = (float)(si0 + 4 * q + r + 1) * (1.0f / 64.0f);

    // bias (+ te/pos rank-2 fold for hidden layers) on primal rows
#pragma unroll
    for (int j = 0; j < 4; j++) {
        float bv = bb[nb + 16 * j + c16];
        if constexpr (!L0) bv += w0te[j];
#pragma unroll
        for (int r = 0; r < 4; r++)
            acc[0][j][r] += L0 ? bv : fmaf(posr[r], w1v[j], bv);
    }

    // wave-local LN stats (6 sums per token over this wave's 64 cols) — DPP all-reduce
    float st[4][6];
#pragma unroll
    for (int r = 0; r < 4; r++) {
        float s1 = 0.f, s2 = 0.f, a0 = 0.f, x0 = 0.f, a1 = 0.f, x1 = 0.f;
#pragma unroll
        for (int j = 0; j < 4; j++) {
            float p  = acc[0][j][r];
            float u0 = L0 ? tu0[j] : acc[1 % MT][j][r];
            float u1 = L0 ? tu1[j] : acc[2 % MT][j][r];
            s1 += p; s2 += p * p;
            a0 += u0; x0 += p * u0;
            a1 += u1; x1 += p * u1;
        }
        st[r][0] = s1; st[r][1] = s2; st[r][2] = a0; st[r][3] = x0; st[r][4] = a1; st[r][5] = x1;
    }
#pragma unroll
    for (int r = 0; r < 4; r++)
#pragma unroll
        for (int s = 0; s < 6; s++) st[r][s] = sum16(st[r][s]);
    if (c16 == 0) {
#pragma unroll
        for (int r = 0; r < 4; r++) {
            int tok = 4 * q + r;
            *(float4*)&sbuf[tok * 68 + w * 8]     = (float4){st[r][0], st[r][1], st[r][2], st[r][3]};
            *(float2*)&sbuf[tok * 68 + w * 8 + 4] = (float2){st[r][4], st[r][5]};
        }
    }
    __syncthreads();   // barrier A: sbuf cross-wave; also fences GEMM A_s reads

    // finalize: wave-redundant (every wave, lanes 0-15), wave-private pwave.
    if (lane < 16) {
        int tok = lane;
        float s0 = 0.f, s1 = 0.f, s2 = 0.f, s3 = 0.f, s4 = 0.f, s5 = 0.f;
#pragma unroll
        for (int ww = 0; ww < 8; ww++) {
            float4 a = *(const float4*)&sbuf[tok * 68 + ww * 8];
            float2 b = *(const float2*)&sbuf[tok * 68 + ww * 8 + 4];
            s0 += a.x; s1 += a.y; s2 += a.z; s3 += a.w; s4 += b.x; s5 += b.y;
        }
        const float inv = 1.0f / 512.0f;
        float mu  = s0 * inv;
        float var = s1 * inv - mu * mu;
        float rs  = rsqrtf(var + EPS);
        float dm0 = s2 * inv, dm1 = s4 * inv;
        float c0 = rs * (s3 * inv - mu * dm0);
        float c1 = rs * (s5 * inv - mu * dm1);
        *(float4*)&pwave[(w * 16 + tok) * 8]     = (float4){mu, rs, dm0, c0};
        *(float4*)&pwave[(w * 16 + tok) * 8 + 4] = (float4){dm1, c1, 0.f, 0.f};
    }

    // epilogue: softplus(LN) + JVP; non-LAST writes bf16 to A_s (PERMUTED:
    // lane's 4 j-outputs contiguous at k' = nb + 4*c16 -> one b64 per row),
    // LAST fuses the W3 dot (full f32) into per-wave partials.
    float gv[4], bvv[4];
#pragma unroll
    for (int j = 0; j < 4; j++) {
        gv[j]  = gg[nb + 16 * j + c16];
        bvv[j] = bev[nb + 16 * j + c16];
    }
#pragma unroll
    for (int r = 0; r < 4; r++) {
        int tok = 4 * q + r;
        float4 pa = *(const float4*)&pwave[(w * 16 + tok) * 8];
        float4 pb = *(const float4*)&pwave[(w * 16 + tok) * 8 + 4];
        float mu = pa.x, rs = pa.y, dm0 = pa.z, c0 = pa.w;
        float dm1 = pb.x, c1 = pb.y;
        float spv[4], d0v[4], d1v[4];
        float a0p = 0.f, a1p = 0.f, dvp = 0.f;
#pragma unroll
        for (int j = 0; j < 4; j++) {
            float p  = acc[0][j][r];
            float u0 = L0 ? tu0[j] : acc[1 % MT][j][r];
            float u1 = L0 ? tu1[j] : acc[2 % MT][j][r];
            float xh = (p - mu) * rs;
            float y  = fmaf(xh, gv[j], bvv[j]);
            float e  = __expf(-fabsf(y));
            float ope  = 1.0f + e;
            float rinv = fastrcp(ope);
            float sig  = (y >= 0.f) ? rinv : e * rinv;
            float sp   = fmaxf(y, 0.f) + __logf(ope);
            float sgrs = sig * (gv[j] * rs);
            float d0 = sgrs * fmaf(-xh, c0, u0 - dm0);
            float d1 = sgrs * fmaf(-xh, c1, u1 - dm1);
            if constexpr (LAST) {
                float2 wv = *(const float2*)&W3s[(2 + nb + 16 * j + c16) * 2];
                a0p = fmaf(sp, wv.x, a0p);
                a1p = fmaf(sp, wv.y, a1p);
                dvp = fmaf(d0, wv.x, dvp);
                dvp = fmaf(d1, wv.y, dvp);
            } else {
                spv[j] = sp; d0v[j] = d0; d1v[j] = d1;
            }
        }
        if constexpr (LAST) {
            a0p = sum16(a0p); a1p = sum16(a1p); dvp = sum16(dvp);
            if (c16 == 0) {
                dsum[tok * 36 + w * 4 + 0] = a0p;
                dsum[tok * 36 + w * 4 + 1] = a1p;
                dsum[tok * 36 + w * 4 + 2] = dvp;
            }
        } else {
            // k' = nb + 4*c16 + j  (permuted; Wt for the next layer matches)
            ushort_t* xr = A_s + tok * SROW + nb + 4 * c16;
            *(uint2*)xr               = (uint2){pk_bf16(spv[0], spv[1]), pk_bf16(spv[2], spv[3])};
            *(uint2*)(xr + 16 * SROW) = (uint2){pk_bf16(d0v[0], d0v[1]), pk_bf16(d0v[2], d0v[3])};
            *(uint2*)(xr + 32 * SROW) = (uint2){pk_bf16(d1v[0], d1v[1]), pk_bf16(d1v[2], d1v[3])};
        }
    }
    __syncthreads();   // barrier B: A_s (non-LAST) / dsum (LAST) cross-wave
}

__global__ __launch_bounds__(512, 4) void ode_mfma(
    const float* __restrict__ t, const float* __restrict__ z,
    const ushort_t* __restrict__ condbf,
    const ushort_t* __restrict__ Wt0, const ushort_t* __restrict__ Wt1, const ushort_t* __restrict__ Wt2,
    const float* __restrict__ W0full, const float* __restrict__ W1full, const float* __restrict__ W2full,
    const float* __restrict__ b0, const float* __restrict__ g0, const float* __restrict__ be0,
    const float* __restrict__ b1, const float* __restrict__ g1, const float* __restrict__ be1,
    const float* __restrict__ b2, const float* __restrict__ g2, const float* __restrict__ be2,
    const float* __restrict__ W3, const float* __restrict__ b3,
    float* __restrict__ out)
{
    __shared__ ushort_t A_s[48 * SROW];     // rows 0..15 primal x, 16..31 u0, 32..47 u1
    __shared__ float sbuf[16 * 68];         // [tok][w*8+s], stride 68 -> 2-way banks
    __shared__ float pwave[8 * 16 * 8];     // wave-private LN params [w][tok][8]
    __shared__ float dsum[16 * 36];         // [tok][w*4+c] L3 partials, stride 36
    __shared__ float W3s[514 * 2];          // staged W3 (row-major [514][2])
    // 2 blocks/CU (reg-capped: 64 arch VGPR + 64 AGPR = 128/wave -> 4 waves/SIMD).

    const int tid = threadIdx.x;
    const float te = t[0];

    // ---------------- init: targeted zeroing + data + W3 staging, ONE barrier ----
    if (tid < 256) {
        int row = tid >> 4, k2 = tid & 15;
        *(uint_t*)(A_s + row * SROW + 132 + 2 * k2) = 0u;   // L0 primal pad k[132,164)
    }
    if (tid < TM) {
        int tok = tid;
        int gm  = blockIdx.x * TM + tok;
        int si  = gm & 63;
        float pos = (float)(si + 1) * (1.0f / 64.0f);
        A_s[tok * SROW + 0] = f2bf(te);
        A_s[tok * SROW + 1] = f2bf(pos);
        A_s[tok * SROW + 2] = f2bf(z[gm * 2 + 0]);
        A_s[tok * SROW + 3] = f2bf(z[gm * 2 + 1]);
    }
    {   // cond: pre-converted bf16, all 16 tokens share one batch row (16 | 64)
        int bi = (blockIdx.x * TM) >> 6;
        const uint_t* cb = (const uint_t*)(condbf + bi * 128);
        for (int i = tid; i < TM * 64; i += 512) {
            int tok = i >> 6, c2 = i & 63;
            *(uint_t*)(A_s + tok * SROW + 4 + 2 * c2) = cb[c2];
        }
    }
    for (int i = tid; i < 514 * 2; i += 512) W3s[i] = W3[i];
    __syncthreads();

    do_layer<K0P, true , false>(Wt0, W0full, te, b0, g0, be0, A_s, sbuf, pwave, nullptr, nullptr);
    do_layer<KHS, false, false>(Wt1, W1full, te, b1, g1, be1, A_s, sbuf, pwave, nullptr, nullptr);
    do_layer<KHS, false, true >(Wt2, W2full, te, b2, g2, be2, A_s, sbuf, pwave, dsum, W3s);

    // ---------------- final cross-wave reduce of L3 partials ----------------
    if (tid < 64) {
        int tok = tid >> 2, c = tid & 3;
        if (c < 3) {
            float s = 0.f;
#pragma unroll
            for (int ww = 0; ww < 8; ww++) s += dsum[tok * 36 + ww * 4 + c];
            int gm = blockIdx.x * TM + tok;
            if (c == 0) {
                float pos = (float)((gm & 63) + 1) * (1.0f / 64.0f);
                out[gm * 2 + 0] = s + te * W3s[0] + pos * W3s[2] + b3[0];
            } else if (c == 1) {
                float pos = (float)((gm & 63) + 1) * (1.0f / 64.0f);
                out[gm * 2 + 1] = s + te * W3s[1] + pos * W3s[3] + b3[1];
            } else {
                out[NTOK * 2 + gm] = -s;
            }
        }
    }
}

extern "C" void kernel_launch(void* const* d_in, const int* in_sizes, int n_in,
                              void* d_out, int out_size, void* d_ws, size_t ws_size,
                              hipStream_t stream) {
    const float* t    = (const float*)d_in[0];
    const float* z    = (const float*)d_in[1];
    const float* cond = (const float*)d_in[2];
    const float* W0   = (const float*)d_in[3];
    const float* b0   = (const float*)d_in[4];
    const float* g0   = (const float*)d_in[5];
    const float* be0  = (const float*)d_in[6];
    const float* W1   = (const float*)d_in[7];
    const float* b1   = (const float*)d_in[8];
    const float* g1   = (const float*)d_in[9];
    const float* be1  = (const float*)d_in[10];
    const float* W2   = (const float*)d_in[11];
    const float* b2   = (const float*)d_in[12];
    const float* g2   = (const float*)d_in[13];
    const float* be2  = (const float*)d_in[14];
    const float* W3   = (const float*)d_in[15];
    const float* b3   = (const float*)d_in[16];
    float* out = (float*)d_out;

    ushort_t* Wt0    = (ushort_t*)d_ws;                 // 512*160
    ushort_t* Wt1    = Wt0 + 512 * K0P;                 // 512*544 (stride 544, data 512, PERMUTED)
    ushort_t* Wt2    = Wt1 + 512 * KHS;                 // 512*544 (PERMUTED)
    ushort_t* condbf = Wt2 + 512 * KHS;                 // 2048*128 bf16

    hipLaunchKernelGGL(prep_w, dim3(512), dim3(256), 0, stream, W0, Wt0, 132, K0P);
    // hidden layers: rows 0,1 (te,pos) folded into the epilogue bias; k-PERMUTED
    hipLaunchKernelGGL(prep_w_h, dim3(512), dim3(256), 0, stream, W1 + 2 * 512, Wt1);
    hipLaunchKernelGGL(prep_w_h, dim3(512), dim3(256), 0, stream, W2 + 2 * 512, Wt2);
    hipLaunchKernelGGL(prep_cond, dim3(256), dim3(256), 0, stream, cond, condbf, 2048 * 128);

    hipLaunchKernelGGL(ode_mfma, dim3(NTOK / TM), dim3(512), 0, stream,
                       t, z, condbf, Wt0, Wt1, Wt2, W0, W1, W2,
                       b0, g0, be0, b1, g1, be1, b2, g2, be2, W3, b3, out);
}

// Round 7
// 669.756 us; speedup vs baseline: 1.2679x; 1.2679x over previous
//
#include <hip/hip_runtime.h>
#include <math.h>

typedef unsigned short ushort_t;
typedef unsigned int uint_t;
typedef __attribute__((ext_vector_type(8))) short bf16x8;
typedef __attribute__((ext_vector_type(4))) float f32x4;

#define NTOK 131072          // B*S
#define TM 16                // tokens per block
// SROW 520: 1040 B row = 65*16 -> b128 16B-aligned; 260 dw == 4 mod 32 -> free
// 2-way bank pattern (the structural minimum for wave64 b128).
#define SROW 520
#define K0P 160              // layer0 K extent padded (132 -> 160), NKS0 = 5
#define EPS 1e-5f

// ---------------------------------------------------------------------------
// B-layout (R7): FRAGMENT-MAJOR Wt. R4->R5 showed the kernel is acutely
// sensitive to B-load service time (pow2 stride cost +370us at equal work);
// the old [n][k] layout made every B-fragment load a 64-lane gather with
// 1088B lane stride (64 scattered 16B transactions / instr). New layout:
//   Wt[w][ks][j][lane][8e]  (lane = q*16+c16)
// so the load for (w,ks,j) is lane-consecutive 16B -> one dense 1KB block.
// Same instruction count / registers / numerics; pure address permutation.
// Hidden layers keep the R6 k'-permutation (A_s store order); L0 unpermuted.
// ---------------------------------------------------------------------------

__device__ __forceinline__ ushort_t f2bf(float f) {
    uint_t x = __float_as_uint(f);
    x += 0x7FFFu + ((x >> 16) & 1u);   // RNE
    return (ushort_t)(x >> 16);
}
__device__ __forceinline__ float bf2f(ushort_t u) {
    return __uint_as_float(((uint_t)u) << 16);
}

#if defined(__has_builtin)
#  if __has_builtin(__builtin_amdgcn_cvt_pk_bf16_f32)
#    define HAVE_PK_BF16 1
#  endif
#  if __has_builtin(__builtin_amdgcn_rcpf)
#    define HAVE_RCPF 1
#  endif
#endif
__device__ __forceinline__ uint_t pk_bf16(float a, float b) {
#ifdef HAVE_PK_BF16
    auto r = __builtin_amdgcn_cvt_pk_bf16_f32(a, b);
    union { decltype(r) v; uint_t u; } cv; cv.v = r;
    return cv.u;
#else
    return (uint_t)f2bf(a) | ((uint_t)f2bf(b) << 16);
#endif
}
// approx reciprocal: v_rcp_f32 (1 op) vs IEEE div (~9 ops). ~1 ulp; outputs
// are bf16-rounded (tol 1.2e-2) so exactness is not needed.
__device__ __forceinline__ float fastrcp(float x) {
#ifdef HAVE_RCPF
    return __builtin_amdgcn_rcpf(x);
#else
    return 1.0f / x;
#endif
}

// ---- DPP 16-lane rotation-reduction (all-reduce within each 16-lane row) ----
template<int CTRL>
__device__ __forceinline__ float row_ror_add(float v) {
    int r = __builtin_amdgcn_update_dpp(0, __float_as_int(v), CTRL, 0xF, 0xF, true);
    return v + __int_as_float(r);
}
__device__ __forceinline__ float sum16(float v) {
    v = row_ror_add<0x128>(v);   // row_ror:8
    v = row_ror_add<0x124>(v);   // row_ror:4
    v = row_ror_add<0x122>(v);   // row_ror:2
    v = row_ror_add<0x121>(v);   // row_ror:1
    return v;
}

// ---- weight prep, layer 0 (fragment-major, unpermuted k, zero-pad >=132) ----
// dst[idx], idx = ((((w*5 + ks)*4 + j)*64 + lane)*8 + e
__global__ __launch_bounds__(256) void prep_w0_frag(const float* __restrict__ W0,
                                                    ushort_t* __restrict__ dst) {
    int idx = blockIdx.x * 256 + threadIdx.x;          // < 512*160 = 81920
    if (idx >= 512 * K0P) return;
    int e = idx & 7, lane = (idx >> 3) & 63, j = (idx >> 9) & 3, t = idx >> 11;
    int ks = t % 5, w = t / 5;
    int kp = ks * 32 + (lane >> 4) * 8 + e;
    int n  = 64 * w + 16 * j + (lane & 15);
    float v = (kp < 132) ? W0[kp * 512 + n] : 0.0f;
    dst[idx] = f2bf(v);
}

// ---- weight prep, hidden (fragment-major + R6 k'-permutation) ----
// Woff = W + 2*512 (te/pos rows folded out).
// k' = kp; source activation col c = 64*(kp>>6) + 16*(kp&3) + ((kp>>2)&15).
__global__ __launch_bounds__(256) void prep_wh_frag(const float* __restrict__ Woff,
                                                    ushort_t* __restrict__ dst) {
    int idx = blockIdx.x * 256 + threadIdx.x;          // < 512*512 = 262144
    int e = idx & 7, lane = (idx >> 3) & 63, j = (idx >> 9) & 3;
    int ks = (idx >> 11) & 15, w = idx >> 15;
    int kp = ks * 32 + (lane >> 4) * 8 + e;
    int c  = 64 * (kp >> 6) + 16 * (kp & 3) + ((kp >> 2) & 15);
    int n  = 64 * w + 16 * j + (lane & 15);
    dst[idx] = f2bf(Woff[c * 512 + n]);
}

// ---- cond prep: B*C f32 -> bf16 once ----
__global__ __launch_bounds__(256) void prep_cond(const float* __restrict__ src,
                                                 ushort_t* __restrict__ dst,
                                                 int n) {
    for (int i = blockIdx.x * 256 + threadIdx.x; i < n; i += gridDim.x * 256)
        dst[i] = f2bf(src[i]);
}

// One fused layer.
//   L0:    tangent GEMMs skipped — tangent pre-acts are W0 rows 2,3 directly.
//   !L0:   GEMM K = 512 (activations only, permuted k'-order; Wt matches).
//          te/pos contribution folded into the epilogue bias (f32-exact).
//   LAST:  fuse the final 514->2 linear + divergence into the epilogue.
// NKS = K-step count (L0: 5, hidden: 16). Wt is fragment-major (see top).
template<int NKS, bool L0, bool LAST>
__device__ __forceinline__ void do_layer(
    const ushort_t* __restrict__ Wt, const float* __restrict__ Wfull, float te,
    const float* __restrict__ bb,
    const float* __restrict__ gg, const float* __restrict__ bev,
    ushort_t* A_s, float* sbuf /*[16][68]*/, float* pwave /*[8][16][8]*/,
    float* dsum /*[16][36]*/, const float* W3s /*[514*2]*/)
{
    const int tid  = threadIdx.x;
    const int w    = tid >> 6;      // wave 0..7
    const int lane = tid & 63;
    const int q    = lane >> 4;     // quad 0..3
    const int c16  = lane & 15;
    const int nb   = w * 64;        // wave's 64-column base

    constexpr int MT = L0 ? 1 : 3;  // m-tiles in the GEMM

    f32x4 acc[MT][4];
#pragma unroll
    for (int m = 0; m < MT; m++)
#pragma unroll
        for (int j = 0; j < 4; j++) acc[m][j] = (f32x4){0.f, 0.f, 0.f, 0.f};

    const int koff = q * 8;
    // fragment-major B: wave base + lane*8; frag (ks,j) at +(ks*4+j)*512 elems
    const ushort_t* bpw = Wt + (size_t)(w * NKS) * 2048 + lane * 8;
    const ushort_t* ap  = A_s + c16 * SROW + koff;

#pragma unroll
    for (int ks = 0; ks < NKS; ks++) {
        bf16x8 af[MT], bf[4];
#pragma unroll
        for (int m = 0; m < MT; m++)
            af[m] = *(const bf16x8*)(ap + m * 16 * SROW + ks * 32);
#pragma unroll
        for (int j = 0; j < 4; j++)
            bf[j] = *(const bf16x8*)(bpw + (ks * 4 + j) * 512);
#pragma unroll
        for (int m = 0; m < MT; m++)
#pragma unroll
            for (int j = 0; j < 4; j++)
                acc[m][j] = __builtin_amdgcn_mfma_f32_16x16x32_bf16(af[m], bf[j], acc[m][j], 0, 0, 0);
    }

    // L0: tangent pre-activations direct from W0 rows 2,3 (token-independent).
    // !L0: te/pos fold vectors from W rows 0,1 (f32, L2-resident).
    float tu0[4], tu1[4];
    float w0te[4], w1v[4];
#pragma unroll
    for (int j = 0; j < 4; j++) {
        int n = nb + 16 * j + c16;
        if constexpr (L0) {
            tu0[j] = Wfull[2 * 512 + n];
            tu1[j] = Wfull[3 * 512 + n];
        } else {
            w0te[j] = te * Wfull[n];        // row 0 (te)
            w1v[j]  = Wfull[512 + n];       // row 1 (pos)
        }
    }

    // per-token pos values for this wave's 4 r-slots (token = 4q+r)
    const int si0 = (blockIdx.x * TM) & 63;     // no wrap within a block (16|64)
    float posr[4];
#pragma unroll
    for (int r = 0; r < 4; r++)
        posr[r] = (float)(si0 + 4 * q + r + 1) * (1.0f / 64.0f);

    // bias (+ te/pos rank-2 fold for hidden layers) on primal rows
#pragma unroll
    for (int j = 0; j < 4; j++) {
        float bv = bb[nb + 16 * j + c16];
        if constexpr (!L0) bv += w0te[j];
#pragma unroll
        for (int r = 0; r < 4; r++)
            acc[0][j][r] += L0 ? bv : fmaf(posr[r], w1v[j], bv);
    }

    // wave-local LN stats (6 sums per token over this wave's 64 cols) — DPP all-reduce
    float st[4][6];
#pragma unroll
    for (int r = 0; r < 4; r++) {
        float s1 = 0.f, s2 = 0.f, a0 = 0.f, x0 = 0.f, a1 = 0.f, x1 = 0.f;
#pragma unroll
        for (int j = 0; j < 4; j++) {
            float p  = acc[0][j][r];
            float u0 = L0 ? tu0[j] : acc[1 % MT][j][r];
            float u1 = L0 ? tu1[j] : acc[2 % MT][j][r];
            s1 += p; s2 += p * p;
            a0 += u0; x0 += p * u0;
            a1 += u1; x1 += p * u1;
        }
        st[r][0] = s1; st[r][1] = s2; st[r][2] = a0; st[r][3] = x0; st[r][4] = a1; st[r][5] = x1;
    }
#pragma unroll
    for (int r = 0; r < 4; r++)
#pragma unroll
        for (int s = 0; s < 6; s++) st[r][s] = sum16(st[r][s]);
    if (c16 == 0) {
#pragma unroll
        for (int r = 0; r < 4; r++) {
            int tok = 4 * q + r;
            *(float4*)&sbuf[tok * 68 + w * 8]     = (float4){st[r][0], st[r][1], st[r][2], st[r][3]};
            *(float2*)&sbuf[tok * 68 + w * 8 + 4] = (float2){st[r][4], st[r][5]};
        }
    }
    __syncthreads();   // barrier A: sbuf cross-wave; also fences GEMM A_s reads

    // finalize: wave-redundant (every wave, lanes 0-15), wave-private pwave.
    if (lane < 16) {
        int tok = lane;
        float s0 = 0.f, s1 = 0.f, s2 = 0.f, s3 = 0.f, s4 = 0.f, s5 = 0.f;
#pragma unroll
        for (int ww = 0; ww < 8; ww++) {
            float4 a = *(const float4*)&sbuf[tok * 68 + ww * 8];
            float2 b = *(const float2*)&sbuf[tok * 68 + ww * 8 + 4];
            s0 += a.x; s1 += a.y; s2 += a.z; s3 += a.w; s4 += b.x; s5 += b.y;
        }
        const float inv = 1.0f / 512.0f;
        float mu  = s0 * inv;
        float var = s1 * inv - mu * mu;
        float rs  = rsqrtf(var + EPS);
        float dm0 = s2 * inv, dm1 = s4 * inv;
        float c0 = rs * (s3 * inv - mu * dm0);
        float c1 = rs * (s5 * inv - mu * dm1);
        *(float4*)&pwave[(w * 16 + tok) * 8]     = (float4){mu, rs, dm0, c0};
        *(float4*)&pwave[(w * 16 + tok) * 8 + 4] = (float4){dm1, c1, 0.f, 0.f};
    }

    // epilogue: softplus(LN) + JVP; non-LAST writes bf16 to A_s (k'-order:
    // lane's 4 j-outputs contiguous at k' = nb + 4*c16 -> one b64 per row),
    // LAST fuses the W3 dot (full f32) into per-wave partials.
    float gv[4], bvv[4];
#pragma unroll
    for (int j = 0; j < 4; j++) {
        gv[j]  = gg[nb + 16 * j + c16];
        bvv[j] = bev[nb + 16 * j + c16];
    }
#pragma unroll
    for (int r = 0; r < 4; r++) {
        int tok = 4 * q + r;
        float4 pa = *(const float4*)&pwave[(w * 16 + tok) * 8];
        float4 pb = *(const float4*)&pwave[(w * 16 + tok) * 8 + 4];
        float mu = pa.x, rs = pa.y, dm0 = pa.z, c0 = pa.w;
        float dm1 = pb.x, c1 = pb.y;
        float spv[4], d0v[4], d1v[4];
        float a0p = 0.f, a1p = 0.f, dvp = 0.f;
#pragma unroll
        for (int j = 0; j < 4; j++) {
            float p  = acc[0][j][r];
            float u0 = L0 ? tu0[j] : acc[1 % MT][j][r];
            float u1 = L0 ? tu1[j] : acc[2 % MT][j][r];
            float xh = (p - mu) * rs;
            float y  = fmaf(xh, gv[j], bvv[j]);
            float e  = __expf(-fabsf(y));
            float ope  = 1.0f + e;
            float rinv = fastrcp(ope);
            float sig  = (y >= 0.f) ? rinv : e * rinv;
            float sp   = fmaxf(y, 0.f) + __logf(ope);
            float sgrs = sig * (gv[j] * rs);
            float d0 = sgrs * fmaf(-xh, c0, u0 - dm0);
            float d1 = sgrs * fmaf(-xh, c1, u1 - dm1);
            if constexpr (LAST) {
                float2 wv = *(const float2*)&W3s[(2 + nb + 16 * j + c16) * 2];
                a0p = fmaf(sp, wv.x, a0p);
                a1p = fmaf(sp, wv.y, a1p);
                dvp = fmaf(d0, wv.x, dvp);
                dvp = fmaf(d1, wv.y, dvp);
            } else {
                spv[j] = sp; d0v[j] = d0; d1v[j] = d1;
            }
        }
        if constexpr (LAST) {
            a0p = sum16(a0p); a1p = sum16(a1p); dvp = sum16(dvp);
            if (c16 == 0) {
                dsum[tok * 36 + w * 4 + 0] = a0p;
                dsum[tok * 36 + w * 4 + 1] = a1p;
                dsum[tok * 36 + w * 4 + 2] = dvp;
            }
        } else {
            // k' = nb + 4*c16 + j  (permuted; Wt for the next layer matches)
            ushort_t* xr = A_s + tok * SROW + nb + 4 * c16;
            *(uint2*)xr               = (uint2){pk_bf16(spv[0], spv[1]), pk_bf16(spv[2], spv[3])};
            *(uint2*)(xr + 16 * SROW) = (uint2){pk_bf16(d0v[0], d0v[1]), pk_bf16(d0v[2], d0v[3])};
            *(uint2*)(xr + 32 * SROW) = (uint2){pk_bf16(d1v[0], d1v[1]), pk_bf16(d1v[2], d1v[3])};
        }
    }
    __syncthreads();   // barrier B: A_s (non-LAST) / dsum (LAST) cross-wave
}

__global__ __launch_bounds__(512, 4) void ode_mfma(
    const float* __restrict__ t, const float* __restrict__ z,
    const ushort_t* __restrict__ condbf,
    const ushort_t* __restrict__ Wt0, const ushort_t* __restrict__ Wt1, const ushort_t* __restrict__ Wt2,
    const float* __restrict__ W0full, const float* __restrict__ W1full, const float* __restrict__ W2full,
    const float* __restrict__ b0, const float* __restrict__ g0, const float* __restrict__ be0,
    const float* __restrict__ b1, const float* __restrict__ g1, const float* __restrict__ be1,
    const float* __restrict__ b2, const float* __restrict__ g2, const float* __restrict__ be2,
    const float* __restrict__ W3, const float* __restrict__ b3,
    float* __restrict__ out)
{
    __shared__ ushort_t A_s[48 * SROW];     // rows 0..15 primal x, 16..31 u0, 32..47 u1
    __shared__ float sbuf[16 * 68];         // [tok][w*8+s], stride 68 -> 2-way banks
    __shared__ float pwave[8 * 16 * 8];     // wave-private LN params [w][tok][8]
    __shared__ float dsum[16 * 36];         // [tok][w*4+c] L3 partials, stride 36
    __shared__ float W3s[514 * 2];          // staged W3 (row-major [514][2])
    // 2 blocks/CU (reg-capped: 64 arch VGPR + 64 AGPR = 128/wave -> 4 waves/SIMD).

    const int tid = threadIdx.x;
    const float te = t[0];

    // ---------------- init: targeted zeroing + data + W3 staging, ONE barrier ----
    if (tid < 256) {
        int row = tid >> 4, k2 = tid & 15;
        *(uint_t*)(A_s + row * SROW + 132 + 2 * k2) = 0u;   // L0 primal pad k[132,164)
    }
    if (tid < TM) {
        int tok = tid;
        int gm  = blockIdx.x * TM + tok;
        int si  = gm & 63;
        float pos = (float)(si + 1) * (1.0f / 64.0f);
        A_s[tok * SROW + 0] = f2bf(te);
        A_s[tok * SROW + 1] = f2bf(pos);
        A_s[tok * SROW + 2] = f2bf(z[gm * 2 + 0]);
        A_s[tok * SROW + 3] = f2bf(z[gm * 2 + 1]);
    }
    {   // cond: pre-converted bf16, all 16 tokens share one batch row (16 | 64)
        int bi = (blockIdx.x * TM) >> 6;
        const uint_t* cb = (const uint_t*)(condbf + bi * 128);
        for (int i = tid; i < TM * 64; i += 512) {
            int tok = i >> 6, c2 = i & 63;
            *(uint_t*)(A_s + tok * SROW + 4 + 2 * c2) = cb[c2];
        }
    }
    for (int i = tid; i < 514 * 2; i += 512) W3s[i] = W3[i];
    __syncthreads();

    do_layer<5 , true , false>(Wt0, W0full, te, b0, g0, be0, A_s, sbuf, pwave, nullptr, nullptr);
    do_layer<16, false, false>(Wt1, W1full, te, b1, g1, be1, A_s, sbuf, pwave, nullptr, nullptr);
    do_layer<16, false, true >(Wt2, W2full, te, b2, g2, be2, A_s, sbuf, pwave, dsum, W3s);

    // ---------------- final cross-wave reduce of L3 partials ----------------
    if (tid < 64) {
        int tok = tid >> 2, c = tid & 3;
        if (c < 3) {
            float s = 0.f;
#pragma unroll
            for (int ww = 0; ww < 8; ww++) s += dsum[tok * 36 + ww * 4 + c];
            int gm = blockIdx.x * TM + tok;
            if (c == 0) {
                float pos = (float)((gm & 63) + 1) * (1.0f / 64.0f);
                out[gm * 2 + 0] = s + te * W3s[0] + pos * W3s[2] + b3[0];
            } else if (c == 1) {
                float pos = (float)((gm & 63) + 1) * (1.0f / 64.0f);
                out[gm * 2 + 1] = s + te * W3s[1] + pos * W3s[3] + b3[1];
            } else {
                out[NTOK * 2 + gm] = -s;
            }
        }
    }
}

extern "C" void kernel_launch(void* const* d_in, const int* in_sizes, int n_in,
                              void* d_out, int out_size, void* d_ws, size_t ws_size,
                              hipStream_t stream) {
    const float* t    = (const float*)d_in[0];
    const float* z    = (const float*)d_in[1];
    const float* cond = (const float*)d_in[2];
    const float* W0   = (const float*)d_in[3];
    const float* b0   = (const float*)d_in[4];
    const float* g0   = (const float*)d_in[5];
    const float* be0  = (const float*)d_in[6];
    const float* W1   = (const float*)d_in[7];
    const float* b1   = (const float*)d_in[8];
    const float* g1   = (const float*)d_in[9];
    const float* be1  = (const float*)d_in[10];
    const float* W2   = (const float*)d_in[11];
    const float* b2   = (const float*)d_in[12];
    const float* g2   = (const float*)d_in[13];
    const float* be2  = (const float*)d_in[14];
    const float* W3   = (const float*)d_in[15];
    const float* b3   = (const float*)d_in[16];
    float* out = (float*)d_out;

    ushort_t* Wt0    = (ushort_t*)d_ws;                 // 512*160  (frag-major)
    ushort_t* Wt1    = Wt0 + 512 * K0P;                 // 512*512  (frag-major, k'-permuted)
    ushort_t* Wt2    = Wt1 + 512 * 512;                 // 512*512
    ushort_t* condbf = Wt2 + 512 * 512;                 // 2048*128 bf16

    hipLaunchKernelGGL(prep_w0_frag, dim3(320), dim3(256), 0, stream, W0, Wt0);
    hipLaunchKernelGGL(prep_wh_frag, dim3(1024), dim3(256), 0, stream, W1 + 2 * 512, Wt1);
    hipLaunchKernelGGL(prep_wh_frag, dim3(1024), dim3(256), 0, stream, W2 + 2 * 512, Wt2);
    hipLaunchKernelGGL(prep_cond, dim3(256), dim3(256), 0, stream, cond, condbf, 2048 * 128);

    hipLaunchKernelGGL(ode_mfma, dim3(NTOK / TM), dim3(512), 0, stream,
                       t, z, condbf, Wt0, Wt1, Wt2, W0, W1, W2,
                       b0, g0, be0, b1, g1, be1, b2, g2, be2, W3, b3, out);
}